// Round 1
// baseline (2031.621 us; speedup 1.0000x reference)
//
#include <hip/hip_runtime.h>
#include <math.h>

#define BN 16
#define T 12
#define CH 128
#define HW 576
#define TM1 11
#define TP 9
#define CCS 114   // channels kept after S_STA=32 cut: 96 v-channels + 18 PE

// ---------------- K0: inverse channel norm per (bt, p) ----------------
__global__ __launch_bounds__(256) void k_invnrm(const float* __restrict__ x,
                                                float* __restrict__ inv_nrm) {
    int idx = blockIdx.x * 256 + threadIdx.x;     // BN*T*HW = 110592
    if (idx >= BN * T * HW) return;
    int p  = idx % HW;
    int bt = idx / HW;
    const float* xp = x + (size_t)bt * CH * HW + p;
    float s = 0.f;
#pragma unroll 8
    for (int c = 0; c < CH; c++) { float v = xp[(size_t)c * HW]; s = fmaf(v, v, s); }
    inv_nrm[idx] = 1.0f / fmaxf(sqrtf(s), 1e-12f);
}

// ---------------- K1: energy GEMM (TN): E[n,m] = scale/temp * invq[n]*invk[m] * sum_c Q[c,n] K[c,m]
// grid (9 ntile, 9 mtile, 176), block 256
__global__ __launch_bounds__(256) void k_energy(const float* __restrict__ x,
                                                const float* __restrict__ inv_nrm,
                                                float* __restrict__ attn,
                                                const int* __restrict__ temp) {
    int z = blockIdx.z; int b = z / TM1; int ti = z % TM1;
    const float* Q = x + (size_t)(b * T + ti + 1) * CH * HW;
    const float* K = x + (size_t)(b * T + ti) * CH * HW;
    int n0 = blockIdx.x * 64, m0 = blockIdx.y * 64;
    const float* invq = inv_nrm + (size_t)(b * T + ti + 1) * HW + n0;
    const float* invk = inv_nrm + (size_t)(b * T + ti) * HW + m0;
    float* E = attn + (size_t)z * HW * HW;

    __shared__ float Qs[16][66];
    __shared__ float Ks[16][66];
    int tid = threadIdx.x;
    int tx = tid % 16, ty = tid / 16;
    int lp = tid % 64, lc = tid / 64;
    float acc[4][4] = {};

    for (int c0 = 0; c0 < CH; c0 += 16) {
#pragma unroll
        for (int i = 0; i < 4; i++) {
            int c = lc + 4 * i;
            Qs[c][lp] = Q[(size_t)(c0 + c) * HW + n0 + lp];
            Ks[c][lp] = K[(size_t)(c0 + c) * HW + m0 + lp];
        }
        __syncthreads();
#pragma unroll
        for (int kk = 0; kk < 16; kk++) {
            float2 a01 = *(const float2*)&Qs[kk][ty * 4];
            float2 a23 = *(const float2*)&Qs[kk][ty * 4 + 2];
            float2 b01 = *(const float2*)&Ks[kk][tx * 4];
            float2 b23 = *(const float2*)&Ks[kk][tx * 4 + 2];
            float av[4] = {a01.x, a01.y, a23.x, a23.y};
            float bw[4] = {b01.x, b01.y, b23.x, b23.y};
#pragma unroll
            for (int i = 0; i < 4; i++)
#pragma unroll
                for (int j = 0; j < 4; j++)
                    acc[i][j] = fmaf(av[i], bw[j], acc[i][j]);
        }
        __syncthreads();
    }
    float sc = 0.08838834764831845f / (float)temp[0];  // ch^-0.5 / temp
#pragma unroll
    for (int i = 0; i < 4; i++) {
        int n = ty * 4 + i;
        float qn = invq[n] * sc;
        float4 o;
        o.x = acc[i][0] * qn * invk[tx * 4 + 0];
        o.y = acc[i][1] * qn * invk[tx * 4 + 1];
        o.z = acc[i][2] * qn * invk[tx * 4 + 2];
        o.w = acc[i][3] * qn * invk[tx * 4 + 3];
        *(float4*)&E[(size_t)(n0 + n) * HW + m0 + tx * 4] = o;
    }
}

// ---------------- K2: softmax in-place over rows of length 576 ----------------
__global__ __launch_bounds__(576) void k_softmax(float* __restrict__ attn) {
    __shared__ float red[9];
    size_t row = blockIdx.x;                 // BN*TM1*HW rows
    float* a = attn + row * HW;
    int t = threadIdx.x;
    float v = a[t];
    float m = v;
#pragma unroll
    for (int i = 1; i < 64; i <<= 1) m = fmaxf(m, __shfl_xor(m, i));
    int wv = t >> 6, ln = t & 63;
    if (ln == 0) red[wv] = m;
    __syncthreads();
    float gm = red[0];
#pragma unroll
    for (int i = 1; i < 9; i++) gm = fmaxf(gm, red[i]);
    float e = __expf(v - gm);
    __syncthreads();
    float s = e;
#pragma unroll
    for (int i = 1; i < 64; i <<= 1) s += __shfl_xor(s, i);
    if (ln == 0) red[wv] = s;
    __syncthreads();
    float gs = red[0];
#pragma unroll
    for (int i = 1; i < 9; i++) gs += red[i];
    a[t] = e / gs;
}

// ---------------- K3: v = Wv[32:128] @ x + bv → cs channels 0..95 ----------------
// grid (9 ntile, 2 mtile, 192), block 256
__global__ __launch_bounds__(256) void k_vgemm(const float* __restrict__ x,
                                               const float* __restrict__ Wv,
                                               const float* __restrict__ bv,
                                               float* __restrict__ cs) {
    int bt = blockIdx.z;
    const float* X = x + (size_t)bt * CH * HW;
    float* C = cs + (size_t)bt * CCS * HW;
    int m0 = blockIdx.y * 64, n0 = blockIdx.x * 64;
    __shared__ float As[16][66];
    __shared__ float Bs[16][66];
    int tid = threadIdx.x;
    int kq = tid % 16, lr = tid / 16;
    int tx = tid % 16, ty = tid / 16;
    int lp = tid % 64, lc = tid / 64;
    float acc[4][4] = {};
    for (int c0 = 0; c0 < CH; c0 += 16) {
#pragma unroll
        for (int i = 0; i < 4; i++) {
            int r = m0 + lr + 16 * i;
            As[kq][lr + 16 * i] = (r < 96) ? Wv[(size_t)(32 + r) * CH + c0 + kq] : 0.f;
        }
#pragma unroll
        for (int i = 0; i < 4; i++) {
            int c = lc + 4 * i;
            Bs[c][lp] = X[(size_t)(c0 + c) * HW + n0 + lp];
        }
        __syncthreads();
#pragma unroll
        for (int kk = 0; kk < 16; kk++) {
            float2 a01 = *(const float2*)&As[kk][ty * 4];
            float2 a23 = *(const float2*)&As[kk][ty * 4 + 2];
            float2 b01 = *(const float2*)&Bs[kk][tx * 4];
            float2 b23 = *(const float2*)&Bs[kk][tx * 4 + 2];
            float av[4] = {a01.x, a01.y, a23.x, a23.y};
            float bw[4] = {b01.x, b01.y, b23.x, b23.y};
#pragma unroll
            for (int i = 0; i < 4; i++)
#pragma unroll
                for (int j = 0; j < 4; j++)
                    acc[i][j] = fmaf(av[i], bw[j], acc[i][j]);
        }
        __syncthreads();
    }
#pragma unroll
    for (int i = 0; i < 4; i++) {
        int r = m0 + ty * 4 + i;
        if (r < 96) {
            float b = bv[32 + r];
            float4 o;
            o.x = acc[i][0] + b; o.y = acc[i][1] + b;
            o.z = acc[i][2] + b; o.w = acc[i][3] + b;
            *(float4*)&C[(size_t)r * HW + n0 + tx * 4] = o;
        }
    }
}

// ---------------- K4: positional encodings → cs channels 96..113 ----------------
__global__ __launch_bounds__(576) void k_pe(float* __restrict__ cs) {
    int bt = blockIdx.x;
    int p = threadIdx.x;
    float* C = cs + ((size_t)bt * CCS + 96) * HW + p;
    int iy = p / 24, ix = p % 24;
    float y = -1.f + 2.f * (float)iy / 23.f;
    float xx = -1.f + 2.f * (float)ix / 23.f;
    C[0] = y;
    C[HW] = xx;
    const float PI = 3.14159265358979323846f;
#pragma unroll
    for (int i = 0; i < 4; i++) {
        float k = (float)(1 << i) * PI;
        float fy = k * y, fx = k * xx;
        C[(size_t)(2 + 4 * i + 0) * HW] = sinf(fy);
        C[(size_t)(2 + 4 * i + 1) * HW] = sinf(fx);
        C[(size_t)(2 + 4 * i + 2) * HW] = cosf(fy);
        C[(size_t)(2 + 4 * i + 3) * HW] = cosf(fx);
    }
}

// ---------------- K5: stage GEMM (NT): prop[r,n] = sum_m A[r,m] * attn[n,m]
// A rows: r<114 from cs[b][tp+shift], else prop_in[z][r-114]
// grid (9 ntile, ceil(M/64), 144), block 256
__global__ __launch_bounds__(256) void k_stage(const float* __restrict__ cs,
                                               const float* __restrict__ prop_in,
                                               const float* __restrict__ attn,
                                               float* __restrict__ dst,
                                               int M, int tshift, int prop_ch,
                                               int dst_stride_ch, int dst_ch_off) {
    int z = blockIdx.z; int b = z / TP; int tp = z % TP;
    const float* csb = cs + (size_t)((b * T + tp + tshift) * CCS) * HW;
    const float* propb = prop_in ? prop_in + (size_t)z * prop_ch * HW : nullptr;
    const float* B = attn + (size_t)(b * TM1 + tp + tshift) * HW * HW;
    int m0 = blockIdx.y * 64, n0 = blockIdx.x * 64;

    __shared__ float As[16][66];
    __shared__ float Bs[16][66];
    int tid = threadIdx.x;
    int kq = tid % 16, lr = tid / 16;
    int tx = tid % 16, ty = tid / 16;
    float acc[4][4] = {};

    const float* arow[4];
#pragma unroll
    for (int i = 0; i < 4; i++) {
        int r = m0 + lr + 16 * i;
        arow[i] = (r < CCS) ? csb + (size_t)r * HW
                            : ((r < M) ? propb + (size_t)(r - CCS) * HW : nullptr);
    }

    for (int k0 = 0; k0 < HW; k0 += 16) {
#pragma unroll
        for (int i = 0; i < 4; i++)
            As[kq][lr + 16 * i] = arow[i] ? arow[i][k0 + kq] : 0.f;
#pragma unroll
        for (int i = 0; i < 4; i++)
            Bs[kq][lr + 16 * i] = B[(size_t)(n0 + lr + 16 * i) * HW + k0 + kq];
        __syncthreads();
#pragma unroll
        for (int kk = 0; kk < 16; kk++) {
            float2 a01 = *(const float2*)&As[kk][ty * 4];
            float2 a23 = *(const float2*)&As[kk][ty * 4 + 2];
            float2 b01 = *(const float2*)&Bs[kk][tx * 4];
            float2 b23 = *(const float2*)&Bs[kk][tx * 4 + 2];
            float av[4] = {a01.x, a01.y, a23.x, a23.y};
            float bw[4] = {b01.x, b01.y, b23.x, b23.y};
#pragma unroll
            for (int i = 0; i < 4; i++)
#pragma unroll
                for (int j = 0; j < 4; j++)
                    acc[i][j] = fmaf(av[i], bw[j], acc[i][j]);
        }
        __syncthreads();
    }

    float* dbase = dst + ((size_t)z * dst_stride_ch + dst_ch_off) * HW;
#pragma unroll
    for (int i = 0; i < 4; i++) {
        int r = m0 + ty * 4 + i;
        if (r < M) {
            float4 o;
            o.x = acc[i][0]; o.y = acc[i][1]; o.z = acc[i][2]; o.w = acc[i][3];
            *(float4*)&dbase[(size_t)r * HW + n0 + tx * 4] = o;
        }
    }
}

// ---------------- K6: copy cs[b][tp+3] → out channels 0..113 ----------------
__global__ __launch_bounds__(256) void k_copy(const float* __restrict__ cs,
                                              float* __restrict__ out) {
    int z = blockIdx.y; int b = z / TP, tp = z % TP;
    int idx = blockIdx.x * 256 + threadIdx.x;
    if (idx >= CCS * HW / 4) return;   // 16416 float4
    const float4* src = (const float4*)(cs + (size_t)((b * T + tp + 3) * CCS) * HW);
    float4* dstp = (float4*)(out + (size_t)z * 456 * HW);
    dstp[idx] = src[idx];
}

extern "C" void kernel_launch(void* const* d_in, const int* in_sizes, int n_in,
                              void* d_out, int out_size, void* d_ws, size_t ws_size,
                              hipStream_t stream) {
    const float* x  = (const float*)d_in[0];
    const float* Wv = (const float*)d_in[1];
    const float* bv = (const float*)d_in[2];
    const int* temp = (const int*)d_in[3];
    float* out = (float*)d_out;

    float* w = (float*)d_ws;
    float* inv_nrm = w;                        // 110,592 f
    float* attn = inv_nrm + 110592;            // 58,392,576 f (176 x 576 x 576)
    float* cs   = attn + 58392576;             // 12,607,488 f (192 x 114 x 576)
    float* p1   = cs + 12607488;               //  9,455,616 f (144 x 114 x 576)
    float* p2   = p1 + 9455616;                // 18,911,232 f (144 x 228 x 576)
    // total: 99,477,504 floats = 398 MB

    k_invnrm<<<432, 256, 0, stream>>>(x, inv_nrm);
    k_energy<<<dim3(9, 9, 176), 256, 0, stream>>>(x, inv_nrm, attn, temp);
    k_softmax<<<BN * TM1 * HW, 576, 0, stream>>>(attn);
    k_vgemm<<<dim3(9, 2, 192), 256, 0, stream>>>(x, Wv, bv, cs);
    k_pe<<<192, 576, 0, stream>>>(cs);
    k_stage<<<dim3(9, 2, 144), 256, 0, stream>>>(cs, nullptr, attn, p1, 114, 0, 0, 114, 0);
    k_stage<<<dim3(9, 4, 144), 256, 0, stream>>>(cs, p1, attn, p2, 228, 1, 114, 228, 0);
    k_stage<<<dim3(9, 6, 144), 256, 0, stream>>>(cs, p2, attn, out, 342, 2, 228, 456, 114);
    k_copy<<<dim3(65, 144), 256, 0, stream>>>(cs, out);
}

// Round 2
// 914.196 us; speedup vs baseline: 2.2223x; 2.2223x over previous
//
#include <hip/hip_runtime.h>
#include <math.h>

#define BN 16
#define T 12
#define CH 128
#define HW 576
#define TM1 11
#define TP 9
#define CCS 114   // channels kept after S_STA=32 cut: 96 v-channels + 18 PE

typedef __attribute__((ext_vector_type(8))) short bf16x8;   // 8 bf16 in 4 VGPRs
typedef __attribute__((ext_vector_type(4))) float floatx4;

typedef unsigned short ushort_t;
typedef unsigned int uint_t;

__device__ inline float b2f(unsigned short u) {
    unsigned int v = ((unsigned int)u) << 16;
    return __builtin_bit_cast(float, v);
}
__device__ inline unsigned short f2b(float f) {
    unsigned int v = __builtin_bit_cast(unsigned int, f);
    unsigned int r = (v + 0x7FFFu + ((v >> 16) & 1u)) >> 16;   // RNE
    return (unsigned short)r;
}

// ---------------- K0: normalize + transpose: xT[bt][p][c] = bf16(x[bt][c][p] / ||x[bt][:,p]||)
__global__ __launch_bounds__(576) void k_norm_t(const float* __restrict__ x,
                                                unsigned short* __restrict__ xT) {
    int bt = blockIdx.x;
    int p = threadIdx.x;
    const float* xp = x + (size_t)bt * CH * HW + p;
    float s = 0.f;
#pragma unroll 8
    for (int c = 0; c < CH; c++) { float v = xp[(size_t)c * HW]; s = fmaf(v, v, s); }
    float inv = 1.0f / fmaxf(sqrtf(s), 1e-12f);
    unsigned short* dst = xT + ((size_t)bt * HW + p) * CH;
    for (int c0 = 0; c0 < CH; c0 += 8) {
        union { unsigned short u[8]; uint4 v; } pk;
#pragma unroll
        for (int j = 0; j < 8; j++) pk.u[j] = f2b(xp[(size_t)(c0 + j) * HW] * inv);
        *(uint4*)(dst + c0) = pk.v;
    }
}

// ---------------- K1: energy MFMA: E[n,m] = sc * sum_c xqT[n,c] * xkT[m,c], bf16 out
// grid (6 mtile, 6 ntile, 176), block 256 (4 waves, 2x2, each 48x48)
__global__ __launch_bounds__(256) void k_energy(const unsigned short* __restrict__ xT,
                                                unsigned short* __restrict__ attn,
                                                const int* __restrict__ temp) {
    int z = blockIdx.z; int b = z / TM1; int ti = z % TM1;
    const unsigned short* Q = xT + (size_t)(b * T + ti + 1) * HW * CH;  // rows n, k=c
    const unsigned short* K = xT + (size_t)(b * T + ti) * HW * CH;      // rows m, k=c
    unsigned short* E = attn + (size_t)z * HW * HW;
    int n0 = blockIdx.y * 96, m0 = blockIdx.x * 96;

    int lane = threadIdx.x & 63;
    int wave = threadIdx.x >> 6;
    int wy = wave >> 1, wx = wave & 1;
    int fr = lane & 15;
    int koff = (lane >> 4) * 8;

    const unsigned short* aptr[3];
    const unsigned short* bptr[3];
#pragma unroll
    for (int i = 0; i < 3; i++) {
        aptr[i] = Q + (size_t)(n0 + wy * 48 + i * 16 + fr) * CH + koff;
        bptr[i] = K + (size_t)(m0 + wx * 48 + i * 16 + fr) * CH + koff;
    }
    floatx4 acc[3][3] = {};
#pragma unroll
    for (int k0 = 0; k0 < CH; k0 += 32) {
        bf16x8 af[3], bfr[3];
#pragma unroll
        for (int i = 0; i < 3; i++) { af[i] = *(const bf16x8*)(aptr[i]); aptr[i] += 32; }
#pragma unroll
        for (int j = 0; j < 3; j++) { bfr[j] = *(const bf16x8*)(bptr[j]); bptr[j] += 32; }
#pragma unroll
        for (int i = 0; i < 3; i++)
#pragma unroll
            for (int j = 0; j < 3; j++)
                acc[i][j] = __builtin_amdgcn_mfma_f32_16x16x32_bf16(af[i], bfr[j], acc[i][j], 0, 0, 0);
    }
    float sc = 0.08838834764831845f / (float)temp[0];
    int crow = (lane >> 4) * 4, ccol = lane & 15;
#pragma unroll
    for (int i = 0; i < 3; i++) {
#pragma unroll
        for (int reg = 0; reg < 4; reg++) {
            int n = n0 + wy * 48 + i * 16 + crow + reg;
#pragma unroll
            for (int j = 0; j < 3; j++) {
                int m = m0 + wx * 48 + j * 16 + ccol;
                E[(size_t)n * HW + m] = f2b(acc[i][j][reg] * sc);
            }
        }
    }
}

// ---------------- K2: softmax in-place over bf16 rows of length 576 ----------------
__global__ __launch_bounds__(576) void k_softmax(unsigned short* __restrict__ attn) {
    __shared__ float red[9];
    size_t row = blockIdx.x;
    unsigned short* a = attn + row * HW;
    int t = threadIdx.x;
    float v = b2f(a[t]);
    float m = v;
#pragma unroll
    for (int i = 1; i < 64; i <<= 1) m = fmaxf(m, __shfl_xor(m, i));
    int wv = t >> 6, ln = t & 63;
    if (ln == 0) red[wv] = m;
    __syncthreads();
    float gm = red[0];
#pragma unroll
    for (int i = 1; i < 9; i++) gm = fmaxf(gm, red[i]);
    float e = __expf(v - gm);
    __syncthreads();
    float s = e;
#pragma unroll
    for (int i = 1; i < 64; i <<= 1) s += __shfl_xor(s, i);
    if (ln == 0) red[wv] = s;
    __syncthreads();
    float gs = red[0];
#pragma unroll
    for (int i = 1; i < 9; i++) gs += red[i];
    a[t] = f2b(e / gs);
}

// ---------------- K3: v = Wv[32:128] @ x + bv → cs (fp32) + cs16 (bf16) ----------------
// grid (9 ntile, 2 mtile, 192), block 256
__global__ __launch_bounds__(256) void k_vgemm(const float* __restrict__ x,
                                               const float* __restrict__ Wv,
                                               const float* __restrict__ bv,
                                               float* __restrict__ cs,
                                               unsigned short* __restrict__ cs16) {
    int bt = blockIdx.z;
    const float* X = x + (size_t)bt * CH * HW;
    float* C = cs + (size_t)bt * CCS * HW;
    unsigned short* C16 = cs16 + (size_t)bt * CCS * HW;
    int m0 = blockIdx.y * 64, n0 = blockIdx.x * 64;
    __shared__ float As[16][66];
    __shared__ float Bs[16][66];
    int tid = threadIdx.x;
    int kq = tid % 16, lr = tid / 16;
    int tx = tid % 16, ty = tid / 16;
    int lp = tid % 64, lc = tid / 64;
    float acc[4][4] = {};
    for (int c0 = 0; c0 < CH; c0 += 16) {
#pragma unroll
        for (int i = 0; i < 4; i++) {
            int r = m0 + lr + 16 * i;
            As[kq][lr + 16 * i] = (r < 96) ? Wv[(size_t)(32 + r) * CH + c0 + kq] : 0.f;
        }
#pragma unroll
        for (int i = 0; i < 4; i++) {
            int c = lc + 4 * i;
            Bs[c][lp] = X[(size_t)(c0 + c) * HW + n0 + lp];
        }
        __syncthreads();
#pragma unroll
        for (int kk = 0; kk < 16; kk++) {
            float2 a01 = *(const float2*)&As[kk][ty * 4];
            float2 a23 = *(const float2*)&As[kk][ty * 4 + 2];
            float2 b01 = *(const float2*)&Bs[kk][tx * 4];
            float2 b23 = *(const float2*)&Bs[kk][tx * 4 + 2];
            float av[4] = {a01.x, a01.y, a23.x, a23.y};
            float bw[4] = {b01.x, b01.y, b23.x, b23.y};
#pragma unroll
            for (int i = 0; i < 4; i++)
#pragma unroll
                for (int j = 0; j < 4; j++)
                    acc[i][j] = fmaf(av[i], bw[j], acc[i][j]);
        }
        __syncthreads();
    }
#pragma unroll
    for (int i = 0; i < 4; i++) {
        int r = m0 + ty * 4 + i;
        if (r < 96) {
            float b = bv[32 + r];
            float4 o;
            o.x = acc[i][0] + b; o.y = acc[i][1] + b;
            o.z = acc[i][2] + b; o.w = acc[i][3] + b;
            *(float4*)&C[(size_t)r * HW + n0 + tx * 4] = o;
            unsigned short* p16 = C16 + (size_t)r * HW + n0 + tx * 4;
            p16[0] = f2b(o.x); p16[1] = f2b(o.y); p16[2] = f2b(o.z); p16[3] = f2b(o.w);
        }
    }
}

// ---------------- K4: positional encodings → cs channels 96..113 (fp32 + bf16) ----------------
__global__ __launch_bounds__(576) void k_pe(float* __restrict__ cs,
                                            unsigned short* __restrict__ cs16) {
    int bt = blockIdx.x;
    int p = threadIdx.x;
    float* C = cs + ((size_t)bt * CCS + 96) * HW + p;
    unsigned short* C16 = cs16 + ((size_t)bt * CCS + 96) * HW + p;
    int iy = p / 24, ix = p % 24;
    float y = -1.f + 2.f * (float)iy / 23.f;
    float xx = -1.f + 2.f * (float)ix / 23.f;
    C[0] = y;   C16[0] = f2b(y);
    C[HW] = xx; C16[HW] = f2b(xx);
    const float PI = 3.14159265358979323846f;
#pragma unroll
    for (int i = 0; i < 4; i++) {
        float k = (float)(1 << i) * PI;
        float fy = k * y, fx = k * xx;
        float v0 = sinf(fy), v1 = sinf(fx), v2 = cosf(fy), v3 = cosf(fx);
        C[(size_t)(2 + 4 * i + 0) * HW] = v0; C16[(size_t)(2 + 4 * i + 0) * HW] = f2b(v0);
        C[(size_t)(2 + 4 * i + 1) * HW] = v1; C16[(size_t)(2 + 4 * i + 1) * HW] = f2b(v1);
        C[(size_t)(2 + 4 * i + 2) * HW] = v2; C16[(size_t)(2 + 4 * i + 2) * HW] = f2b(v2);
        C[(size_t)(2 + 4 * i + 3) * HW] = v3; C16[(size_t)(2 + 4 * i + 3) * HW] = f2b(v3);
    }
}

// ---------------- K5: stage GEMM via MFMA: prop[r,n] = sum_m A[r,m] * attn[n,m]
// A rows r<114 from cs16[b][tp+tshift], else prop_in[z][r-114]. Direct-global frag loads.
// grid (6 ntile(96), mtiles(128), 144), block 256 (4 waves 2x2: wave = 64rows x 48cols)
__global__ __launch_bounds__(256) void k_stage(const unsigned short* __restrict__ cs16,
                                               const unsigned short* __restrict__ prop_in,
                                               const unsigned short* __restrict__ attn,
                                               float* __restrict__ dst_f32,
                                               unsigned short* __restrict__ dst_b16,
                                               int M, int tshift, int prop_ch,
                                               int dst_stride_ch, int dst_ch_off) {
    int z = blockIdx.z; int b = z / TP; int tp = z % TP;
    const unsigned short* csz = cs16 + (size_t)((b * T + tp + tshift) * CCS) * HW;
    const unsigned short* prz = prop_in ? prop_in + (size_t)z * prop_ch * HW : nullptr;
    const unsigned short* B = attn + (size_t)(b * TM1 + tp + tshift) * HW * HW;
    int m0 = blockIdx.y * 128, n0 = blockIdx.x * 96;

    int lane = threadIdx.x & 63;
    int wave = threadIdx.x >> 6;
    int wy = wave >> 1, wx = wave & 1;
    int fr = lane & 15;
    int koff = (lane >> 4) * 8;

    const unsigned short* aptr[4];
#pragma unroll
    for (int i = 0; i < 4; i++) {
        int r = m0 + wy * 64 + i * 16 + fr;
        const unsigned short* p;
        if (r < CCS) p = csz + (size_t)r * HW;
        else if (prz && r < M) p = prz + (size_t)(r - CCS) * HW;
        else p = csz;   // dummy, result never stored
        aptr[i] = p + koff;
    }
    const unsigned short* bptr[3];
#pragma unroll
    for (int j = 0; j < 3; j++)
        bptr[j] = B + (size_t)(n0 + wx * 48 + j * 16 + fr) * HW + koff;

    floatx4 acc[4][3] = {};
    for (int k0 = 0; k0 < HW; k0 += 32) {
        bf16x8 af[4], bfr[3];
#pragma unroll
        for (int i = 0; i < 4; i++) { af[i] = *(const bf16x8*)(aptr[i]); aptr[i] += 32; }
#pragma unroll
        for (int j = 0; j < 3; j++) { bfr[j] = *(const bf16x8*)(bptr[j]); bptr[j] += 32; }
#pragma unroll
        for (int i = 0; i < 4; i++)
#pragma unroll
            for (int j = 0; j < 3; j++)
                acc[i][j] = __builtin_amdgcn_mfma_f32_16x16x32_bf16(af[i], bfr[j], acc[i][j], 0, 0, 0);
    }

    int crow = (lane >> 4) * 4, ccol = lane & 15;
#pragma unroll
    for (int i = 0; i < 4; i++) {
#pragma unroll
        for (int reg = 0; reg < 4; reg++) {
            int r = m0 + wy * 64 + i * 16 + crow + reg;
            if (r < M) {
#pragma unroll
                for (int j = 0; j < 3; j++) {
                    int n = n0 + wx * 48 + j * 16 + ccol;
                    size_t idx = ((size_t)z * dst_stride_ch + dst_ch_off + r) * HW + n;
                    if (dst_f32) dst_f32[idx] = acc[i][j][reg];
                    else dst_b16[idx] = f2b(acc[i][j][reg]);
                }
            }
        }
    }
}

// ---------------- K6: copy cs[b][tp+3] (fp32) → out channels 0..113 ----------------
__global__ __launch_bounds__(256) void k_copy(const float* __restrict__ cs,
                                              float* __restrict__ out) {
    int z = blockIdx.y; int b = z / TP, tp = z % TP;
    int idx = blockIdx.x * 256 + threadIdx.x;
    if (idx >= CCS * HW / 4) return;   // 16416 float4
    const float4* src = (const float4*)(cs + (size_t)((b * T + tp + 3) * CCS) * HW);
    float4* dstp = (float4*)(out + (size_t)z * 456 * HW);
    dstp[idx] = src[idx];
}

extern "C" void kernel_launch(void* const* d_in, const int* in_sizes, int n_in,
                              void* d_out, int out_size, void* d_ws, size_t ws_size,
                              hipStream_t stream) {
    const float* x  = (const float*)d_in[0];
    const float* Wv = (const float*)d_in[1];
    const float* bv = (const float*)d_in[2];
    const int* temp = (const int*)d_in[3];
    float* out = (float*)d_out;

    // workspace layout (bytes):
    char* w = (char*)d_ws;
    unsigned short* xT     = (unsigned short*)w;                 // 192*576*128 ush = 28.3 MB
    w += (size_t)192 * HW * CH * 2;
    unsigned short* attn16 = (unsigned short*)w;                 // 176*576*576 ush = 116.8 MB
    w += (size_t)176 * HW * HW * 2;
    float* cs              = (float*)w;                          // 192*114*576 f = 50.4 MB
    w += (size_t)192 * CCS * HW * 4;
    unsigned short* cs16   = (unsigned short*)w;                 // 25.2 MB
    w += (size_t)192 * CCS * HW * 2;
    unsigned short* p1     = (unsigned short*)w;                 // 144*114*576 ush = 18.9 MB
    w += (size_t)144 * CCS * HW * 2;
    unsigned short* p2     = (unsigned short*)w;                 // 144*228*576 ush = 37.8 MB
    // total ~277 MB

    k_norm_t<<<192, 576, 0, stream>>>(x, xT);
    k_energy<<<dim3(6, 6, 176), 256, 0, stream>>>(xT, attn16, temp);
    k_softmax<<<BN * TM1 * HW, 576, 0, stream>>>(attn16);
    k_vgemm<<<dim3(9, 2, 192), 256, 0, stream>>>(x, Wv, bv, cs, cs16);
    k_pe<<<192, 576, 0, stream>>>(cs, cs16);
    k_stage<<<dim3(6, 1, 144), 256, 0, stream>>>(cs16, nullptr, attn16, nullptr, p1, 114, 0, 0, 114, 0);
    k_stage<<<dim3(6, 2, 144), 256, 0, stream>>>(cs16, p1, attn16, nullptr, p2, 228, 1, 114, 228, 0);
    k_stage<<<dim3(6, 3, 144), 256, 0, stream>>>(cs16, p2, attn16, out, nullptr, 342, 2, 228, 456, 114);
    k_copy<<<dim3(65, 144), 256, 0, stream>>>(cs, out);
}

// Round 3
// 762.888 us; speedup vs baseline: 2.6631x; 1.1983x over previous
//
#include <hip/hip_runtime.h>
#include <math.h>

#define BN 16
#define T 12
#define CH 128
#define HW 576
#define TM1 11
#define TP 9
#define CCS 114   // channels kept after S_STA=32 cut: 96 v-channels + 18 PE

typedef __attribute__((ext_vector_type(8))) short bf16x8;   // 8 bf16 in 4 VGPRs
typedef __attribute__((ext_vector_type(4))) float floatx4;

__device__ inline float b2f(unsigned short u) {
    unsigned int v = ((unsigned int)u) << 16;
    return __builtin_bit_cast(float, v);
}
__device__ inline unsigned short f2b(float f) {
    unsigned int v = __builtin_bit_cast(unsigned int, f);
    unsigned int r = (v + 0x7FFFu + ((v >> 16) & 1u)) >> 16;   // RNE
    return (unsigned short)r;
}

// ---------------- K0: normalize + transpose: xT[bt][p][c] = bf16(x[bt][c][p] / ||x[bt][:,p]||)
__global__ __launch_bounds__(576) void k_norm_t(const float* __restrict__ x,
                                                unsigned short* __restrict__ xT) {
    int bt = blockIdx.x;
    int p = threadIdx.x;
    const float* xp = x + (size_t)bt * CH * HW + p;
    float s = 0.f;
#pragma unroll 8
    for (int c = 0; c < CH; c++) { float v = xp[(size_t)c * HW]; s = fmaf(v, v, s); }
    float inv = 1.0f / fmaxf(sqrtf(s), 1e-12f);
    unsigned short* dst = xT + ((size_t)bt * HW + p) * CH;
    for (int c0 = 0; c0 < CH; c0 += 8) {
        union { unsigned short u[8]; uint4 v; } pk;
#pragma unroll
        for (int j = 0; j < 8; j++) pk.u[j] = f2b(xp[(size_t)(c0 + j) * HW] * inv);
        *(uint4*)(dst + c0) = pk.v;
    }
}

// ---------------- K1: energy MFMA: E[n,m] = sc * sum_c xqT[n,c] * xkT[m,c], bf16 out
// grid (6 mtile, 6 ntile, 176), block 256 (4 waves, 2x2, each 48x48)
__global__ __launch_bounds__(256) void k_energy(const unsigned short* __restrict__ xT,
                                                unsigned short* __restrict__ attn,
                                                const int* __restrict__ temp) {
    int z = blockIdx.z; int b = z / TM1; int ti = z % TM1;
    const unsigned short* Q = xT + (size_t)(b * T + ti + 1) * HW * CH;  // rows n, k=c
    const unsigned short* K = xT + (size_t)(b * T + ti) * HW * CH;      // rows m, k=c
    unsigned short* E = attn + (size_t)z * HW * HW;
    int n0 = blockIdx.y * 96, m0 = blockIdx.x * 96;

    int lane = threadIdx.x & 63;
    int wave = threadIdx.x >> 6;
    int wy = wave >> 1, wx = wave & 1;
    int fr = lane & 15;
    int koff = (lane >> 4) * 8;

    const unsigned short* aptr[3];
    const unsigned short* bptr[3];
#pragma unroll
    for (int i = 0; i < 3; i++) {
        aptr[i] = Q + (size_t)(n0 + wy * 48 + i * 16 + fr) * CH + koff;
        bptr[i] = K + (size_t)(m0 + wx * 48 + i * 16 + fr) * CH + koff;
    }
    floatx4 acc[3][3] = {};
#pragma unroll
    for (int k0 = 0; k0 < CH; k0 += 32) {
        bf16x8 af[3], bfr[3];
#pragma unroll
        for (int i = 0; i < 3; i++) { af[i] = *(const bf16x8*)(aptr[i]); aptr[i] += 32; }
#pragma unroll
        for (int j = 0; j < 3; j++) { bfr[j] = *(const bf16x8*)(bptr[j]); bptr[j] += 32; }
#pragma unroll
        for (int i = 0; i < 3; i++)
#pragma unroll
            for (int j = 0; j < 3; j++)
                acc[i][j] = __builtin_amdgcn_mfma_f32_16x16x32_bf16(af[i], bfr[j], acc[i][j], 0, 0, 0);
    }
    float sc = 0.08838834764831845f / (float)temp[0];
    int crow = (lane >> 4) * 4, ccol = lane & 15;
#pragma unroll
    for (int i = 0; i < 3; i++) {
#pragma unroll
        for (int reg = 0; reg < 4; reg++) {
            int n = n0 + wy * 48 + i * 16 + crow + reg;
#pragma unroll
            for (int j = 0; j < 3; j++) {
                int m = m0 + wx * 48 + j * 16 + ccol;
                E[(size_t)n * HW + m] = f2b(acc[i][j][reg] * sc);
            }
        }
    }
}

// ---------------- K2: softmax in-place, one WAVE per row of 576 (9 elems/lane) ----------------
// grid: 101376/4 blocks, block 256 (4 waves)
__global__ __launch_bounds__(256) void k_softmax(unsigned short* __restrict__ attn) {
    int row = blockIdx.x * 4 + (threadIdx.x >> 6);
    int lane = threadIdx.x & 63;
    unsigned short* a = attn + (size_t)row * HW + lane;

    float v[9];
#pragma unroll
    for (int j = 0; j < 9; j++) v[j] = b2f(a[64 * j]);

    float m = v[0];
#pragma unroll
    for (int j = 1; j < 9; j++) m = fmaxf(m, v[j]);
#pragma unroll
    for (int i = 1; i < 64; i <<= 1) m = fmaxf(m, __shfl_xor(m, i));

    float s = 0.f;
#pragma unroll
    for (int j = 0; j < 9; j++) { v[j] = __expf(v[j] - m); s += v[j]; }
#pragma unroll
    for (int i = 1; i < 64; i <<= 1) s += __shfl_xor(s, i);

    float inv = 1.0f / s;
#pragma unroll
    for (int j = 0; j < 9; j++) a[64 * j] = f2b(v[j] * inv);
}

// ---------------- K3: v = Wv[32:128] @ x + bv → cs (fp32) + cs16 (bf16) ----------------
// grid (9 ntile, 2 mtile, 192), block 256
__global__ __launch_bounds__(256) void k_vgemm(const float* __restrict__ x,
                                               const float* __restrict__ Wv,
                                               const float* __restrict__ bv,
                                               float* __restrict__ cs,
                                               unsigned short* __restrict__ cs16) {
    int bt = blockIdx.z;
    const float* X = x + (size_t)bt * CH * HW;
    float* C = cs + (size_t)bt * CCS * HW;
    unsigned short* C16 = cs16 + (size_t)bt * CCS * HW;
    int m0 = blockIdx.y * 64, n0 = blockIdx.x * 64;
    __shared__ float As[16][66];
    __shared__ float Bs[16][66];
    int tid = threadIdx.x;
    int kq = tid % 16, lr = tid / 16;
    int tx = tid % 16, ty = tid / 16;
    int lp = tid % 64, lc = tid / 64;
    float acc[4][4] = {};
    for (int c0 = 0; c0 < CH; c0 += 16) {
#pragma unroll
        for (int i = 0; i < 4; i++) {
            int r = m0 + lr + 16 * i;
            As[kq][lr + 16 * i] = (r < 96) ? Wv[(size_t)(32 + r) * CH + c0 + kq] : 0.f;
        }
#pragma unroll
        for (int i = 0; i < 4; i++) {
            int c = lc + 4 * i;
            Bs[c][lp] = X[(size_t)(c0 + c) * HW + n0 + lp];
        }
        __syncthreads();
#pragma unroll
        for (int kk = 0; kk < 16; kk++) {
            float2 a01 = *(const float2*)&As[kk][ty * 4];
            float2 a23 = *(const float2*)&As[kk][ty * 4 + 2];
            float2 b01 = *(const float2*)&Bs[kk][tx * 4];
            float2 b23 = *(const float2*)&Bs[kk][tx * 4 + 2];
            float av[4] = {a01.x, a01.y, a23.x, a23.y};
            float bw[4] = {b01.x, b01.y, b23.x, b23.y};
#pragma unroll
            for (int i = 0; i < 4; i++)
#pragma unroll
                for (int j = 0; j < 4; j++)
                    acc[i][j] = fmaf(av[i], bw[j], acc[i][j]);
        }
        __syncthreads();
    }
#pragma unroll
    for (int i = 0; i < 4; i++) {
        int r = m0 + ty * 4 + i;
        if (r < 96) {
            float b = bv[32 + r];
            float4 o;
            o.x = acc[i][0] + b; o.y = acc[i][1] + b;
            o.z = acc[i][2] + b; o.w = acc[i][3] + b;
            *(float4*)&C[(size_t)r * HW + n0 + tx * 4] = o;
            unsigned short* p16 = C16 + (size_t)r * HW + n0 + tx * 4;
            p16[0] = f2b(o.x); p16[1] = f2b(o.y); p16[2] = f2b(o.z); p16[3] = f2b(o.w);
        }
    }
}

// ---------------- K4: positional encodings → cs channels 96..113 (fp32 + bf16) ----------------
__global__ __launch_bounds__(576) void k_pe(float* __restrict__ cs,
                                            unsigned short* __restrict__ cs16) {
    int bt = blockIdx.x;
    int p = threadIdx.x;
    float* C = cs + ((size_t)bt * CCS + 96) * HW + p;
    unsigned short* C16 = cs16 + ((size_t)bt * CCS + 96) * HW + p;
    int iy = p / 24, ix = p % 24;
    float y = -1.f + 2.f * (float)iy / 23.f;
    float xx = -1.f + 2.f * (float)ix / 23.f;
    C[0] = y;   C16[0] = f2b(y);
    C[HW] = xx; C16[HW] = f2b(xx);
    const float PI = 3.14159265358979323846f;
#pragma unroll
    for (int i = 0; i < 4; i++) {
        float k = (float)(1 << i) * PI;
        float fy = k * y, fx = k * xx;
        float v0 = sinf(fy), v1 = sinf(fx), v2 = cosf(fy), v3 = cosf(fx);
        C[(size_t)(2 + 4 * i + 0) * HW] = v0; C16[(size_t)(2 + 4 * i + 0) * HW] = f2b(v0);
        C[(size_t)(2 + 4 * i + 1) * HW] = v1; C16[(size_t)(2 + 4 * i + 1) * HW] = f2b(v1);
        C[(size_t)(2 + 4 * i + 2) * HW] = v2; C16[(size_t)(2 + 4 * i + 2) * HW] = f2b(v2);
        C[(size_t)(2 + 4 * i + 3) * HW] = v3; C16[(size_t)(2 + 4 * i + 3) * HW] = f2b(v3);
    }
}

// ---------------- K5: stage GEMM via MFMA: prop[r,n] = sum_m A[r,m] * attn[n,m]
// A rows r<114 from cs16[b][tp+tshift], else prop_in[z][r-114]. Direct-global frag loads.
// grid (6 ntile(96), mtiles(128), 144), block 256 (4 waves 2x2: wave = 64rows x 48cols)
__global__ __launch_bounds__(256) void k_stage(const unsigned short* __restrict__ cs16,
                                               const unsigned short* __restrict__ prop_in,
                                               const unsigned short* __restrict__ attn,
                                               float* __restrict__ dst_f32,
                                               unsigned short* __restrict__ dst_b16,
                                               int M, int tshift, int prop_ch,
                                               int dst_stride_ch, int dst_ch_off) {
    int z = blockIdx.z; int b = z / TP; int tp = z % TP;
    const unsigned short* csz = cs16 + (size_t)((b * T + tp + tshift) * CCS) * HW;
    const unsigned short* prz = prop_in ? prop_in + (size_t)z * prop_ch * HW : nullptr;
    const unsigned short* B = attn + (size_t)(b * TM1 + tp + tshift) * HW * HW;
    int m0 = blockIdx.y * 128, n0 = blockIdx.x * 96;

    int lane = threadIdx.x & 63;
    int wave = threadIdx.x >> 6;
    int wy = wave >> 1, wx = wave & 1;
    int fr = lane & 15;
    int koff = (lane >> 4) * 8;

    const unsigned short* aptr[4];
#pragma unroll
    for (int i = 0; i < 4; i++) {
        int r = m0 + wy * 64 + i * 16 + fr;
        const unsigned short* p;
        if (r < CCS) p = csz + (size_t)r * HW;
        else if (prz && r < M) p = prz + (size_t)(r - CCS) * HW;
        else p = csz;   // dummy, result never stored
        aptr[i] = p + koff;
    }
    const unsigned short* bptr[3];
#pragma unroll
    for (int j = 0; j < 3; j++)
        bptr[j] = B + (size_t)(n0 + wx * 48 + j * 16 + fr) * HW + koff;

    floatx4 acc[4][3] = {};
    for (int k0 = 0; k0 < HW; k0 += 32) {
        bf16x8 af[4], bfr[3];
#pragma unroll
        for (int i = 0; i < 4; i++) { af[i] = *(const bf16x8*)(aptr[i]); aptr[i] += 32; }
#pragma unroll
        for (int j = 0; j < 3; j++) { bfr[j] = *(const bf16x8*)(bptr[j]); bptr[j] += 32; }
#pragma unroll
        for (int i = 0; i < 4; i++)
#pragma unroll
            for (int j = 0; j < 3; j++)
                acc[i][j] = __builtin_amdgcn_mfma_f32_16x16x32_bf16(af[i], bfr[j], acc[i][j], 0, 0, 0);
    }

    int crow = (lane >> 4) * 4, ccol = lane & 15;
#pragma unroll
    for (int i = 0; i < 4; i++) {
#pragma unroll
        for (int reg = 0; reg < 4; reg++) {
            int r = m0 + wy * 64 + i * 16 + crow + reg;
            if (r < M) {
#pragma unroll
                for (int j = 0; j < 3; j++) {
                    int n = n0 + wx * 48 + j * 16 + ccol;
                    size_t idx = ((size_t)z * dst_stride_ch + dst_ch_off + r) * HW + n;
                    if (dst_f32) dst_f32[idx] = acc[i][j][reg];
                    else dst_b16[idx] = f2b(acc[i][j][reg]);
                }
            }
        }
    }
}

// ---------------- K6: copy cs[b][tp+3] (fp32) → out channels 0..113 ----------------
__global__ __launch_bounds__(256) void k_copy(const float* __restrict__ cs,
                                              float* __restrict__ out) {
    int z = blockIdx.y; int b = z / TP, tp = z % TP;
    int idx = blockIdx.x * 256 + threadIdx.x;
    if (idx >= CCS * HW / 4) return;   // 16416 float4
    const float4* src = (const float4*)(cs + (size_t)((b * T + tp + 3) * CCS) * HW);
    float4* dstp = (float4*)(out + (size_t)z * 456 * HW);
    dstp[idx] = src[idx];
}

extern "C" void kernel_launch(void* const* d_in, const int* in_sizes, int n_in,
                              void* d_out, int out_size, void* d_ws, size_t ws_size,
                              hipStream_t stream) {
    const float* x  = (const float*)d_in[0];
    const float* Wv = (const float*)d_in[1];
    const float* bv = (const float*)d_in[2];
    const int* temp = (const int*)d_in[3];
    float* out = (float*)d_out;

    // workspace layout (bytes):
    char* w = (char*)d_ws;
    unsigned short* xT     = (unsigned short*)w;                 // 192*576*128 ush = 28.3 MB
    w += (size_t)192 * HW * CH * 2;
    unsigned short* attn16 = (unsigned short*)w;                 // 176*576*576 ush = 116.8 MB
    w += (size_t)176 * HW * HW * 2;
    float* cs              = (float*)w;                          // 192*114*576 f = 50.4 MB
    w += (size_t)192 * CCS * HW * 4;
    unsigned short* cs16   = (unsigned short*)w;                 // 25.2 MB
    w += (size_t)192 * CCS * HW * 2;
    unsigned short* p1     = (unsigned short*)w;                 // 144*114*576 ush = 18.9 MB
    w += (size_t)144 * CCS * HW * 2;
    unsigned short* p2     = (unsigned short*)w;                 // 144*228*576 ush = 37.8 MB
    // total ~277 MB

    k_norm_t<<<192, 576, 0, stream>>>(x, xT);
    k_energy<<<dim3(6, 6, 176), 256, 0, stream>>>(xT, attn16, temp);
    k_softmax<<<BN * TM1 * HW / 4, 256, 0, stream>>>(attn16);
    k_vgemm<<<dim3(9, 2, 192), 256, 0, stream>>>(x, Wv, bv, cs, cs16);
    k_pe<<<192, 576, 0, stream>>>(cs, cs16);
    k_stage<<<dim3(6, 1, 144), 256, 0, stream>>>(cs16, nullptr, attn16, nullptr, p1, 114, 0, 0, 114, 0);
    k_stage<<<dim3(6, 2, 144), 256, 0, stream>>>(cs16, p1, attn16, nullptr, p2, 228, 1, 114, 228, 0);
    k_stage<<<dim3(6, 3, 144), 256, 0, stream>>>(cs16, p2, attn16, out, nullptr, 342, 2, 228, 456, 114);
    k_copy<<<dim3(65, 144), 256, 0, stream>>>(cs, out);
}

// Round 5
// 736.010 us; speedup vs baseline: 2.7603x; 1.0365x over previous
//
#include <hip/hip_runtime.h>
#include <math.h>

#define BN 16
#define T 12
#define CH 128
#define HW 576
#define TM1 11
#define TP 9
#define CCS 114   // channels kept after S_STA=32 cut: 96 v-channels + 18 PE

typedef __attribute__((ext_vector_type(8))) short bf16x8;   // 8 bf16 in 4 VGPRs
typedef __attribute__((ext_vector_type(4))) float floatx4;

__device__ inline float b2f(unsigned short u) {
    unsigned int v = ((unsigned int)u) << 16;
    return __builtin_bit_cast(float, v);
}
__device__ inline unsigned short f2b(float f) {
    unsigned int v = __builtin_bit_cast(unsigned int, f);
    unsigned int r = (v + 0x7FFFu + ((v >> 16) & 1u)) >> 16;   // RNE
    return (unsigned short)r;
}

// ---------------- K0: normalize + transpose: xT[bt][p][c] = bf16(x[bt][c][p] / ||x[bt][:,p]||)
__global__ __launch_bounds__(576) void k_norm_t(const float* __restrict__ x,
                                                unsigned short* __restrict__ xT) {
    int bt = blockIdx.x;
    int p = threadIdx.x;
    const float* xp = x + (size_t)bt * CH * HW + p;
    float s = 0.f;
#pragma unroll 8
    for (int c = 0; c < CH; c++) { float v = xp[(size_t)c * HW]; s = fmaf(v, v, s); }
    float inv = 1.0f / fmaxf(sqrtf(s), 1e-12f);
    unsigned short* dst = xT + ((size_t)bt * HW + p) * CH;
    for (int c0 = 0; c0 < CH; c0 += 8) {
        union { unsigned short u[8]; uint4 v; } pk;
#pragma unroll
        for (int j = 0; j < 8; j++) pk.u[j] = f2b(xp[(size_t)(c0 + j) * HW] * inv);
        *(uint4*)(dst + c0) = pk.v;
    }
}

// ---------------- K1: energy MFMA: E[n,m] = sc * sum_c xqT[n,c] * xkT[m,c], bf16 out
// grid (6 mtile, 6 ntile, 176), block 256 (4 waves, 2x2, each 48x48)
__global__ __launch_bounds__(256) void k_energy(const unsigned short* __restrict__ xT,
                                                unsigned short* __restrict__ attn,
                                                const int* __restrict__ temp) {
    int z = blockIdx.z; int b = z / TM1; int ti = z % TM1;
    const unsigned short* Q = xT + (size_t)(b * T + ti + 1) * HW * CH;  // rows n, k=c
    const unsigned short* K = xT + (size_t)(b * T + ti) * HW * CH;      // rows m, k=c
    unsigned short* E = attn + (size_t)z * HW * HW;
    int n0 = blockIdx.y * 96, m0 = blockIdx.x * 96;

    int lane = threadIdx.x & 63;
    int wave = threadIdx.x >> 6;
    int wy = wave >> 1, wx = wave & 1;
    int fr = lane & 15;
    int koff = (lane >> 4) * 8;

    const unsigned short* aptr[3];
    const unsigned short* bptr[3];
#pragma unroll
    for (int i = 0; i < 3; i++) {
        aptr[i] = Q + (size_t)(n0 + wy * 48 + i * 16 + fr) * CH + koff;
        bptr[i] = K + (size_t)(m0 + wx * 48 + i * 16 + fr) * CH + koff;
    }
    floatx4 acc[3][3] = {};
#pragma unroll
    for (int k0 = 0; k0 < CH; k0 += 32) {
        bf16x8 af[3], bfr[3];
#pragma unroll
        for (int i = 0; i < 3; i++) { af[i] = *(const bf16x8*)(aptr[i]); aptr[i] += 32; }
#pragma unroll
        for (int j = 0; j < 3; j++) { bfr[j] = *(const bf16x8*)(bptr[j]); bptr[j] += 32; }
#pragma unroll
        for (int i = 0; i < 3; i++)
#pragma unroll
            for (int j = 0; j < 3; j++)
                acc[i][j] = __builtin_amdgcn_mfma_f32_16x16x32_bf16(af[i], bfr[j], acc[i][j], 0, 0, 0);
    }
    float sc = 0.08838834764831845f / (float)temp[0];
    int crow = (lane >> 4) * 4, ccol = lane & 15;
#pragma unroll
    for (int i = 0; i < 3; i++) {
#pragma unroll
        for (int reg = 0; reg < 4; reg++) {
            int n = n0 + wy * 48 + i * 16 + crow + reg;
#pragma unroll
            for (int j = 0; j < 3; j++) {
                int m = m0 + wx * 48 + j * 16 + ccol;
                E[(size_t)n * HW + m] = f2b(acc[i][j][reg] * sc);
            }
        }
    }
}

// ---------------- K2: softmax in-place, one WAVE per row of 576 (9 elems/lane) ----------------
__global__ __launch_bounds__(256) void k_softmax(unsigned short* __restrict__ attn) {
    int row = blockIdx.x * 4 + (threadIdx.x >> 6);
    int lane = threadIdx.x & 63;
    unsigned short* a = attn + (size_t)row * HW + lane;

    float v[9];
#pragma unroll
    for (int j = 0; j < 9; j++) v[j] = b2f(a[64 * j]);

    float m = v[0];
#pragma unroll
    for (int j = 1; j < 9; j++) m = fmaxf(m, v[j]);
#pragma unroll
    for (int i = 1; i < 64; i <<= 1) m = fmaxf(m, __shfl_xor(m, i));

    float s = 0.f;
#pragma unroll
    for (int j = 0; j < 9; j++) { v[j] = __expf(v[j] - m); s += v[j]; }
#pragma unroll
    for (int i = 1; i < 64; i <<= 1) s += __shfl_xor(s, i);

    float inv = 1.0f / s;
#pragma unroll
    for (int j = 0; j < 9; j++) a[64 * j] = f2b(v[j] * inv);
}

// ---------------- K3: v = Wv[32:128] @ x + bv → cs16 (bf16) + direct out ch 0..95 for t>=3
// grid (9 ntile, 2 mtile, 192), block 256
__global__ __launch_bounds__(256) void k_vgemm(const float* __restrict__ x,
                                               const float* __restrict__ Wv,
                                               const float* __restrict__ bv,
                                               unsigned short* __restrict__ cs16,
                                               float* __restrict__ out) {
    int bt = blockIdx.z;
    int b = bt / T, t = bt % T;
    const float* X = x + (size_t)bt * CH * HW;
    unsigned short* C16 = cs16 + (size_t)bt * CCS * HW;
    float* O = (t >= 3) ? out + (size_t)(b * TP + t - 3) * 456 * HW : nullptr;
    int m0 = blockIdx.y * 64, n0 = blockIdx.x * 64;
    __shared__ float As[16][66];
    __shared__ float Bs[16][66];
    int tid = threadIdx.x;
    int kq = tid % 16, lr = tid / 16;
    int tx = tid % 16, ty = tid / 16;
    int lp = tid % 64, lc = tid / 64;
    float acc[4][4] = {};
    for (int c0 = 0; c0 < CH; c0 += 16) {
#pragma unroll
        for (int i = 0; i < 4; i++) {
            int r = m0 + lr + 16 * i;
            As[kq][lr + 16 * i] = (r < 96) ? Wv[(size_t)(32 + r) * CH + c0 + kq] : 0.f;
        }
#pragma unroll
        for (int i = 0; i < 4; i++) {
            int c = lc + 4 * i;
            Bs[c][lp] = X[(size_t)(c0 + c) * HW + n0 + lp];
        }
        __syncthreads();
#pragma unroll
        for (int kk = 0; kk < 16; kk++) {
            float2 a01 = *(const float2*)&As[kk][ty * 4];
            float2 a23 = *(const float2*)&As[kk][ty * 4 + 2];
            float2 b01 = *(const float2*)&Bs[kk][tx * 4];
            float2 b23 = *(const float2*)&Bs[kk][tx * 4 + 2];
            float av[4] = {a01.x, a01.y, a23.x, a23.y};
            float bw[4] = {b01.x, b01.y, b23.x, b23.y};
#pragma unroll
            for (int i = 0; i < 4; i++)
#pragma unroll
                for (int j = 0; j < 4; j++)
                    acc[i][j] = fmaf(av[i], bw[j], acc[i][j]);
        }
        __syncthreads();
    }
#pragma unroll
    for (int i = 0; i < 4; i++) {
        int r = m0 + ty * 4 + i;
        if (r < 96) {
            float bb = bv[32 + r];
            floatx4 o;
            o[0] = acc[i][0] + bb; o[1] = acc[i][1] + bb;
            o[2] = acc[i][2] + bb; o[3] = acc[i][3] + bb;
            union { unsigned short u[4]; uint2 v; } pk;
            pk.u[0] = f2b(o[0]); pk.u[1] = f2b(o[1]); pk.u[2] = f2b(o[2]); pk.u[3] = f2b(o[3]);
            *(uint2*)(C16 + (size_t)r * HW + n0 + tx * 4) = pk.v;
            if (O) __builtin_nontemporal_store(o, (floatx4*)(O + (size_t)r * HW + n0 + tx * 4));
        }
    }
}

// ---------------- K4: positional encodings → cs16 ch 96..113 + direct out for t>=3 ----------------
__global__ __launch_bounds__(576) void k_pe(unsigned short* __restrict__ cs16,
                                            float* __restrict__ out) {
    int bt = blockIdx.x;
    int b = bt / T, t = bt % T;
    int p = threadIdx.x;
    unsigned short* C16 = cs16 + ((size_t)bt * CCS + 96) * HW + p;
    float* O = (t >= 3) ? out + ((size_t)(b * TP + t - 3) * 456 + 96) * HW + p : nullptr;
    int iy = p / 24, ix = p % 24;
    float y = -1.f + 2.f * (float)iy / 23.f;
    float xx = -1.f + 2.f * (float)ix / 23.f;
    float vals[18];
    vals[0] = y; vals[1] = xx;
    const float PI = 3.14159265358979323846f;
#pragma unroll
    for (int i = 0; i < 4; i++) {
        float k = (float)(1 << i) * PI;
        float fy = k * y, fx = k * xx;
        vals[2 + 4 * i + 0] = sinf(fy);
        vals[2 + 4 * i + 1] = sinf(fx);
        vals[2 + 4 * i + 2] = cosf(fy);
        vals[2 + 4 * i + 3] = cosf(fx);
    }
#pragma unroll
    for (int c = 0; c < 18; c++) {
        C16[(size_t)c * HW] = f2b(vals[c]);
        if (O) __builtin_nontemporal_store(vals[c], O + (size_t)c * HW);
    }
}

// ---------------- K5: stage GEMM via MFMA: prop[r,n] = sum_m A[r,m] * attn[n,m]
// ONE m-tile: block covers full M (waves stacked on M, frag f = wave + 4*i), n-tile 64.
// grid (9 ntile, 1, 144), block 256. attn read exactly once per z per stage.
template<int M_, bool F32OUT>
__global__ __launch_bounds__(256) void k_stage(const unsigned short* __restrict__ cs16,
                                               const unsigned short* __restrict__ prop_in,
                                               const unsigned short* __restrict__ attn,
                                               float* __restrict__ dst_f32,
                                               unsigned short* __restrict__ dst_b16,
                                               int tshift, int prop_ch,
                                               int dst_stride_ch, int dst_ch_off) {
    constexpr int MF = (M_ + 15) / 16;   // 16-row fragments
    constexpr int NF = (MF + 3) / 4;     // max fragments per wave
    int z = blockIdx.z; int b = z / TP; int tp = z % TP;
    const unsigned short* csz = cs16 + (size_t)((b * T + tp + tshift) * CCS) * HW;
    const unsigned short* prz = prop_in ? prop_in + (size_t)z * prop_ch * HW : csz;
    const unsigned short* B = attn + (size_t)(b * TM1 + tp + tshift) * HW * HW;
    int n0 = blockIdx.x * 64;

    int lane = threadIdx.x & 63;
    int wave = threadIdx.x >> 6;
    int fr = lane & 15;
    int koff = (lane >> 4) * 8;

    const unsigned short* aptr[NF];
#pragma unroll
    for (int i = 0; i < NF; i++) {
        int r = (wave + 4 * i) * 16 + fr;
        const unsigned short* p;
        if (r < CCS) p = csz + (size_t)r * HW;
        else if (r < M_) p = prz + (size_t)(r - CCS) * HW;
        else p = csz;   // dummy, result never stored
        aptr[i] = p + koff;
    }
    const unsigned short* bptr[4];
#pragma unroll
    for (int j = 0; j < 4; j++)
        bptr[j] = B + (size_t)(n0 + j * 16 + fr) * HW + koff;

    floatx4 acc[NF][4] = {};
    for (int k0 = 0; k0 < HW; k0 += 32) {
        bf16x8 af[NF], bfr[4];
#pragma unroll
        for (int i = 0; i < NF; i++) { af[i] = *(const bf16x8*)(aptr[i]); aptr[i] += 32; }
#pragma unroll
        for (int j = 0; j < 4; j++) { bfr[j] = *(const bf16x8*)(bptr[j]); bptr[j] += 32; }
#pragma unroll
        for (int i = 0; i < NF; i++)
#pragma unroll
            for (int j = 0; j < 4; j++)
                acc[i][j] = __builtin_amdgcn_mfma_f32_16x16x32_bf16(af[i], bfr[j], acc[i][j], 0, 0, 0);
    }

    int crow = (lane >> 4) * 4, ccol = lane & 15;
#pragma unroll
    for (int i = 0; i < NF; i++) {
#pragma unroll
        for (int reg = 0; reg < 4; reg++) {
            int r = (wave + 4 * i) * 16 + crow + reg;
            if (r < M_) {
#pragma unroll
                for (int j = 0; j < 4; j++) {
                    int n = n0 + j * 16 + ccol;
                    size_t idx = ((size_t)z * dst_stride_ch + dst_ch_off + r) * HW + n;
                    if (F32OUT) __builtin_nontemporal_store(acc[i][j][reg], dst_f32 + idx);
                    else dst_b16[idx] = f2b(acc[i][j][reg]);
                }
            }
        }
    }
}

extern "C" void kernel_launch(void* const* d_in, const int* in_sizes, int n_in,
                              void* d_out, int out_size, void* d_ws, size_t ws_size,
                              hipStream_t stream) {
    const float* x  = (const float*)d_in[0];
    const float* Wv = (const float*)d_in[1];
    const float* bv = (const float*)d_in[2];
    const int* temp = (const int*)d_in[3];
    float* out = (float*)d_out;

    // workspace layout (bytes):
    char* w = (char*)d_ws;
    unsigned short* xT     = (unsigned short*)w;                 // 192*576*128 ush = 28.3 MB
    w += (size_t)192 * HW * CH * 2;
    unsigned short* attn16 = (unsigned short*)w;                 // 176*576*576 ush = 116.8 MB
    w += (size_t)176 * HW * HW * 2;
    unsigned short* cs16   = (unsigned short*)w;                 // 25.2 MB
    w += (size_t)192 * CCS * HW * 2;
    unsigned short* p1     = (unsigned short*)w;                 // 144*114*576 ush = 18.9 MB
    w += (size_t)144 * CCS * HW * 2;
    unsigned short* p2     = (unsigned short*)w;                 // 144*228*576 ush = 37.8 MB
    // total ~227 MB

    k_norm_t<<<192, 576, 0, stream>>>(x, xT);
    k_energy<<<dim3(6, 6, 176), 256, 0, stream>>>(xT, attn16, temp);
    k_softmax<<<BN * TM1 * HW / 4, 256, 0, stream>>>(attn16);
    k_vgemm<<<dim3(9, 2, 192), 256, 0, stream>>>(x, Wv, bv, cs16, out);
    k_pe<<<192, 576, 0, stream>>>(cs16, out);
    k_stage<114, false><<<dim3(9, 1, 144), 256, 0, stream>>>(cs16, nullptr, attn16, nullptr, p1, 0, 0, 114, 0);
    k_stage<228, false><<<dim3(9, 1, 144), 256, 0, stream>>>(cs16, p1, attn16, nullptr, p2, 1, 114, 228, 0);
    k_stage<342, true ><<<dim3(9, 1, 144), 256, 0, stream>>>(cs16, p2, attn16, out, nullptr, 2, 228, 456, 114);
}